// Round 12
// baseline (339.619 us; speedup 1.0000x reference)
//
#include <hip/hip_runtime.h>

#define D 128
#define CAP 48            // per-node slot capacity; max degree ~36 for Poisson(16)
#define PSHIFT 8
#define PNODES 256        // nodes per partition
#define PMAX 512          // compile-time max partitions (N <= 131072)
#define CAPP 6144         // per-partition edge capacity (mean 4092, sigma ~64)
#define EPB 8192          // edges per k_part block

typedef unsigned short u16;
typedef __bf16 bf16_t;
typedef bf16_t bf16x8 __attribute__((ext_vector_type(8)));
typedef float f32x4v __attribute__((ext_vector_type(4)));

// ---------------- bf16 helpers ----------------

__device__ __forceinline__ u16 f2bf(float f) {           // RNE
    unsigned u = __float_as_uint(f);
    return (u16)((u + 0x7FFFu + ((u >> 16) & 1u)) >> 16);
}

__device__ __forceinline__ float bf2f(u16 h) {
    return __uint_as_float((unsigned)h << 16);
}

__device__ __forceinline__ float4 bf2f4(ushort4 h) {
    float4 f;
    f.x = bf2f(h.x); f.y = bf2f(h.y); f.z = bf2f(h.z); f.w = bf2f(h.w);
    return f;
}

__device__ __forceinline__ void fma4(float4& acc, float xs, const float4& wv) {
    acc.x = fmaf(xs, wv.x, acc.x);
    acc.y = fmaf(xs, wv.y, acc.y);
    acc.z = fmaf(xs, wv.z, acc.z);
    acc.w = fmaf(xs, wv.w, acc.w);
}

// ---------------- build phase A: LDS-privatized radix partition ----------------

__global__ __launch_bounds__(1024) void k_part(const int* __restrict__ src,
                                               const int* __restrict__ dstv,
                                               int* __restrict__ pcur,
                                               int* __restrict__ plist, int E, int P) {
    __shared__ int hist_l[PMAX];
    __shared__ int base_l[PMAX];
    int e0 = blockIdx.x * EPB;
    int e1 = min(e0 + EPB, E);

    for (int i = threadIdx.x; i < P; i += 1024) hist_l[i] = 0;
    __syncthreads();

    for (int e = e0 + threadIdx.x; e < e1; e += 1024)
        atomicAdd(&hist_l[dstv[e] >> PSHIFT], 1);
    __syncthreads();

    for (int i = threadIdx.x; i < P; i += 1024)
        base_l[i] = atomicAdd(&pcur[i], hist_l[i]);
    __syncthreads();

    for (int e = e0 + threadIdx.x; e < e1; e += 1024) {
        int s = src[e], d = dstv[e];
        int p = d >> PSHIFT;
        int pos = atomicAdd(&base_l[p], 1);   // LDS atomic
        if (pos < CAPP)
            plist[(size_t)p * CAPP + pos] = (s << PSHIFT) | (d & (PNODES - 1));
    }
}

// ---------------- build phase B: per-partition slot build in LDS (+dis) ----------------

__global__ __launch_bounds__(256) void k_build2(const int* __restrict__ plist,
                                                const int* __restrict__ pcur,
                                                int* __restrict__ cnt,
                                                int* __restrict__ slots,
                                                float* __restrict__ dis, int N) {
    __shared__ int cnt_l[PNODES];          // 1 KB
    __shared__ int slots_l[PNODES * CAP];  // 48 KB
    int p = blockIdx.x;
    int node0 = p << PSHIFT;
    int nnodes = min(PNODES, N - node0);

    for (int t = threadIdx.x; t < PNODES; t += 256) cnt_l[t] = 0;
    __syncthreads();

    int nE = min(pcur[p], CAPP);
    for (int i = threadIdx.x; i < nE; i += 256) {
        int v = plist[(size_t)p * CAPP + i];
        int ln = v & (PNODES - 1);
        int s = (unsigned)v >> PSHIFT;
        int q = atomicAdd(&cnt_l[ln], 1);  // LDS atomic
        if (q < CAP) slots_l[ln * CAP + q] = s;
    }
    __syncthreads();

    for (int t = threadIdx.x; t < nnodes; t += 256) {
        int c = cnt_l[t];
        cnt[node0 + t] = c;
        dis[node0 + t] = rsqrtf((float)(c + 1));  // deg = indeg + self-loop
    }
    int tot = nnodes * CAP;
    int* gs = slots + (size_t)node0 * CAP;
    for (int i = threadIdx.x; i < tot; i += 256) gs[i] = slots_l[i];
}

// ---------------- degree counting-sort: perm groups equal-degree nodes ----------------
// Co-scheduled agg half-waves then have equal loop counts (removes the
// max-degree straggler tax; Poisson 17 +- 4 -> ~25% waste).

__global__ __launch_bounds__(1024) void k_dhist(const int* __restrict__ cnt,
                                                int* __restrict__ dhist, int N) {
    __shared__ int h[64];
    if (threadIdx.x < 64) h[threadIdx.x] = 0;
    __syncthreads();
    int i = blockIdx.x * 1024 + threadIdx.x;
    if (i < N) atomicAdd(&h[min(cnt[i], CAP)], 1);
    __syncthreads();
    if (threadIdx.x < 64 && h[threadIdx.x]) atomicAdd(&dhist[threadIdx.x], h[threadIdx.x]);
}

__global__ void k_dscan(const int* __restrict__ dhist, int* __restrict__ dbase) {
    if (threadIdx.x == 0) {
        int acc = 0;
        for (int b = 0; b < 64; ++b) { dbase[b] = acc; acc += dhist[b]; }
    }
}

__global__ __launch_bounds__(1024) void k_dscatter(const int* __restrict__ cnt,
                                                   int* __restrict__ dbase,
                                                   int* __restrict__ perm, int N) {
    __shared__ int h[64], base[64];
    if (threadIdx.x < 64) h[threadIdx.x] = 0;
    __syncthreads();
    int i = blockIdx.x * 1024 + threadIdx.x;
    int b = 0;
    if (i < N) { b = min(cnt[i], CAP); atomicAdd(&h[b], 1); }
    __syncthreads();
    if (threadIdx.x < 64 && h[threadIdx.x]) base[threadIdx.x] = atomicAdd(&dbase[threadIdx.x], h[threadIdx.x]);
    __syncthreads();
    if (threadIdx.x < 64) h[threadIdx.x] = 0;
    __syncthreads();
    if (i < N) {
        int pos = base[b] + atomicAdd(&h[b], 1);
        perm[pos] = i;
    }
}

// ---------------- MFMA GEMM: H(bf16) = X(fp32) @ W via split-bf16 ----------------

__global__ __launch_bounds__(256) void k_gemm(const float* __restrict__ X,
                                              const float* __restrict__ Wg,
                                              u16* __restrict__ H, int nchunks, int N) {
    __shared__ bf16_t sHi[D * D];  // 32 KB, W^T [n][k], swizzled
    __shared__ bf16_t sLo[D * D];  // 32 KB

    for (int i = threadIdx.x; i < D * D; i += 256) {
        int k = i >> 7, n = i & 127;        // Wg[i] = W[k][n], coalesced in n
        float w = Wg[i];
        bf16_t hi = (bf16_t)w;
        bf16_t lo = (bf16_t)(w - (float)hi);
        int idx = (n * D + k) ^ ((n & 7) << 3);
        sHi[idx] = hi;
        sLo[idx] = lo;
    }
    __syncthreads();

    int wv = threadIdx.x >> 6;   // wave 0..3
    int l  = threadIdx.x & 63;
    int lm = l & 15;             // A-row / B-col / C-col within tile
    int g  = l >> 4;             // k-group (A/B), row-group (C/D)

    for (int chunk = blockIdx.x; chunk < nchunks; chunk += gridDim.x) {
        int rowbase = chunk * 128 + wv * 32;
        if (rowbase >= N) continue;

        f32x4v acc[2][8];
#pragma unroll
        for (int rt = 0; rt < 2; ++rt)
#pragma unroll
            for (int c = 0; c < 8; ++c)
#pragma unroll
                for (int r = 0; r < 4; ++r) acc[rt][c][r] = 0.f;

#pragma unroll
        for (int t = 0; t < 4; ++t) {
            bf16x8 ahi[2], alo[2];
#pragma unroll
            for (int rt = 0; rt < 2; ++rt) {
                int row = rowbase + rt * 16 + lm;
                int rc = row < N ? row : N - 1;          // clamp: loads safe, stores guarded
                const float4* xp = (const float4*)(X + (size_t)rc * D + t * 32 + g * 8);
                float4 f0 = xp[0];
                float4 f1 = xp[1];
                float fv[8] = {f0.x, f0.y, f0.z, f0.w, f1.x, f1.y, f1.z, f1.w};
#pragma unroll
                for (int i = 0; i < 8; ++i) {
                    bf16_t hb = (bf16_t)fv[i];
                    ahi[rt][i] = hb;
                    alo[rt][i] = (bf16_t)(fv[i] - (float)hb);
                }
            }
#pragma unroll
            for (int c = 0; c < 8; ++c) {
                int idx = ((c * 16 + lm) * D + t * 32 + g * 8) ^ ((lm & 7) << 3);
                bf16x8 bhi = *(const bf16x8*)&sHi[idx];
                bf16x8 blo = *(const bf16x8*)&sLo[idx];
                acc[0][c] = __builtin_amdgcn_mfma_f32_16x16x32_bf16(ahi[0], bhi, acc[0][c], 0, 0, 0);
                acc[0][c] = __builtin_amdgcn_mfma_f32_16x16x32_bf16(ahi[0], blo, acc[0][c], 0, 0, 0);
                acc[0][c] = __builtin_amdgcn_mfma_f32_16x16x32_bf16(alo[0], bhi, acc[0][c], 0, 0, 0);
                acc[1][c] = __builtin_amdgcn_mfma_f32_16x16x32_bf16(ahi[1], bhi, acc[1][c], 0, 0, 0);
                acc[1][c] = __builtin_amdgcn_mfma_f32_16x16x32_bf16(ahi[1], blo, acc[1][c], 0, 0, 0);
                acc[1][c] = __builtin_amdgcn_mfma_f32_16x16x32_bf16(alo[1], bhi, acc[1][c], 0, 0, 0);
            }
        }

#pragma unroll
        for (int rt = 0; rt < 2; ++rt)
#pragma unroll
            for (int r = 0; r < 4; ++r) {
                int row = rowbase + rt * 16 + g * 4 + r;
                if (row >= N) continue;
                u16* hp = H + (size_t)row * D + lm;
#pragma unroll
                for (int c = 0; c < 8; ++c)
                    hp[c * 16] = f2bf(acc[rt][c][r]);
            }
    }
}

// ---------------- Aggregation: Y(fp32) = A_norm @ H(bf16) + b ----------------
// Half-wave per node (via degree-sorted perm); unroll 16/8/4/1.

__global__ __launch_bounds__(256) void k_agg(const u16* __restrict__ H,
                                             const int* __restrict__ slots,
                                             const int* __restrict__ cnt,
                                             const float* __restrict__ dis,
                                             const float* __restrict__ perm,
                                             const float* __restrict__ bias,
                                             float* __restrict__ Y, int N, int relu) {
    int hw = (blockIdx.x * 256 + threadIdx.x) >> 5;
    int lane = threadIdx.x & 31;
    if (hw >= N) return;
    int node = ((const int*)perm)[hw];

    const ushort4* __restrict__ Hv = (const ushort4*)H;  // 32 ushort4 per row

    float ds = dis[node];
    float4 hv = bf2f4(Hv[(size_t)node * 32 + lane]);
    float wl = ds * ds;  // self-loop norm
    float4 acc;
    acc.x = wl * hv.x; acc.y = wl * hv.y; acc.z = wl * hv.z; acc.w = wl * hv.w;

    int n = cnt[node];
    if (n > CAP) n = CAP;
    const int* sp = slots + (size_t)node * CAP;

    int e = 0;
    for (; e + 16 <= n; e += 16) {
        int ss[16]; ushort4 vv[16]; float ww[16];
#pragma unroll
        for (int j = 0; j < 16; ++j) ss[j] = sp[e + j];
#pragma unroll
        for (int j = 0; j < 16; ++j) vv[j] = Hv[(size_t)ss[j] * 32 + lane];
#pragma unroll
        for (int j = 0; j < 16; ++j) ww[j] = dis[ss[j]] * ds;
#pragma unroll
        for (int j = 0; j < 16; ++j) fma4(acc, ww[j], bf2f4(vv[j]));
    }
    for (; e + 8 <= n; e += 8) {
        int ss[8]; ushort4 vv[8]; float ww[8];
#pragma unroll
        for (int j = 0; j < 8; ++j) ss[j] = sp[e + j];
#pragma unroll
        for (int j = 0; j < 8; ++j) vv[j] = Hv[(size_t)ss[j] * 32 + lane];
#pragma unroll
        for (int j = 0; j < 8; ++j) ww[j] = dis[ss[j]] * ds;
#pragma unroll
        for (int j = 0; j < 8; ++j) fma4(acc, ww[j], bf2f4(vv[j]));
    }
    for (; e + 4 <= n; e += 4) {
        int ss[4]; ushort4 vv[4]; float ww[4];
#pragma unroll
        for (int j = 0; j < 4; ++j) ss[j] = sp[e + j];
#pragma unroll
        for (int j = 0; j < 4; ++j) vv[j] = Hv[(size_t)ss[j] * 32 + lane];
#pragma unroll
        for (int j = 0; j < 4; ++j) ww[j] = dis[ss[j]] * ds;
#pragma unroll
        for (int j = 0; j < 4; ++j) fma4(acc, ww[j], bf2f4(vv[j]));
    }
    for (; e < n; ++e) {
        int s = sp[e];
        ushort4 v = Hv[(size_t)s * 32 + lane];
        fma4(acc, dis[s] * ds, bf2f4(v));
    }

    float4 bv = ((const float4*)bias)[lane];
    acc.x += bv.x; acc.y += bv.y; acc.z += bv.z; acc.w += bv.w;
    if (relu) {
        acc.x = fmaxf(acc.x, 0.f);
        acc.y = fmaxf(acc.y, 0.f);
        acc.z = fmaxf(acc.z, 0.f);
        acc.w = fmaxf(acc.w, 0.f);
    }
    ((float4*)(Y + (size_t)node * D))[lane] = acc;
}

// ---------------- launch ----------------

extern "C" void kernel_launch(void* const* d_in, const int* in_sizes, int n_in,
                              void* d_out, int out_size, void* d_ws, size_t ws_size,
                              hipStream_t stream) {
    const float* x  = (const float*)d_in[0];
    const int*   ei = (const int*)d_in[1];
    const float* W1 = (const float*)d_in[2];
    const float* b1 = (const float*)d_in[3];
    const float* W2 = (const float*)d_in[4];
    const float* b2 = (const float*)d_in[5];
    const float* W3 = (const float*)d_in[6];
    const float* b3 = (const float*)d_in[7];
    float* out = (float*)d_out;

    int N = in_sizes[0] / D;
    int E = in_sizes[1] / 2;
    const int* src  = ei;       // edge_index[0]
    const int* dstv = ei + E;   // edge_index[1]
    int P = (N + PNODES - 1) >> PSHIFT;  // 391

    char* ws = (char*)d_ws;
    size_t off = 0;
    auto alloc = [&](size_t bytes) -> void* {
        void* p = ws + off;
        off += (bytes + 255) & ~(size_t)255;
        return p;
    };
    u16*   Hbuf  = (u16*)alloc((size_t)N * D * sizeof(u16));        // 25.6 MB
    int*   cnt   = (int*)alloc((size_t)N * sizeof(int));            // 0.4 MB
    int*   slots = (int*)alloc((size_t)N * CAP * sizeof(int));      // 19.2 MB
    float* dis   = (float*)alloc((size_t)N * sizeof(float));        // 0.4 MB
    int*   pcur  = (int*)alloc((size_t)P * sizeof(int));            // 1.6 KB
    int*   plist = (int*)alloc((size_t)P * CAPP * sizeof(int));     // 9.6 MB
    int*   perm  = (int*)alloc((size_t)N * sizeof(int));            // 0.4 MB
    int*   dhist = (int*)alloc(64 * sizeof(int));
    int*   dbase = (int*)alloc(64 * sizeof(int));

    int nchunks = (N + 127) / 128;   // 782 chunks of 128 rows
    int gemmgrid = (nchunks + 1) / 2;  // 391: exactly 2 chunks per block
    int aggblocks = (N + 7) / 8;
    int pablocks = (E + EPB - 1) / EPB;  // 196
    int nb1k = (N + 1023) / 1024;

    // --- build: partition -> LDS slot build(+dis) -> degree sort ---
    hipMemsetAsync(pcur, 0, (size_t)P * sizeof(int), stream);
    hipMemsetAsync(dhist, 0, 64 * sizeof(int), stream);
    k_part<<<pablocks, 1024, 0, stream>>>(src, dstv, pcur, plist, E, P);
    k_build2<<<P, 256, 0, stream>>>(plist, pcur, cnt, slots, dis, N);
    k_dhist<<<nb1k, 1024, 0, stream>>>(cnt, dhist, N);
    k_dscan<<<1, 64, 0, stream>>>(dhist, dbase);
    k_dscatter<<<nb1k, 1024, 0, stream>>>(cnt, dbase, perm, N);

    // --- layer 1 ---
    k_gemm<<<gemmgrid, 256, 0, stream>>>(x, W1, Hbuf, nchunks, N);
    k_agg<<<aggblocks, 256, 0, stream>>>(Hbuf, slots, cnt, dis, (const float*)perm, b1, out, N, 1);

    // --- layer 2 ---
    k_gemm<<<gemmgrid, 256, 0, stream>>>(out, W2, Hbuf, nchunks, N);
    k_agg<<<aggblocks, 256, 0, stream>>>(Hbuf, slots, cnt, dis, (const float*)perm, b2, out, N, 1);

    // --- layer 3 (no relu) ---
    k_gemm<<<gemmgrid, 256, 0, stream>>>(out, W3, Hbuf, nchunks, N);
    k_agg<<<aggblocks, 256, 0, stream>>>(Hbuf, slots, cnt, dis, (const float*)perm, b3, out, N, 0);
}

// Round 13
// 320.518 us; speedup vs baseline: 1.0596x; 1.0596x over previous
//
#include <hip/hip_runtime.h>

#define D 128
#define CAP 48            // per-node slot capacity; max degree ~36 for Poisson(16)
#define PSHIFT 8
#define PNODES 256        // nodes per partition
#define PMAX 512          // compile-time max partitions (N <= 131072)
#define CAPP 6144         // per-partition edge capacity (mean 4092, sigma ~64)
#define EPB 8192          // edges per k_part block

typedef unsigned short u16;
typedef __bf16 bf16_t;
typedef bf16_t bf16x8 __attribute__((ext_vector_type(8)));
typedef float f32x4v __attribute__((ext_vector_type(4)));

// ---------------- bf16 helpers ----------------

__device__ __forceinline__ u16 f2bf(float f) {           // RNE
    unsigned u = __float_as_uint(f);
    return (u16)((u + 0x7FFFu + ((u >> 16) & 1u)) >> 16);
}

__device__ __forceinline__ float bf2f(u16 h) {
    return __uint_as_float((unsigned)h << 16);
}

__device__ __forceinline__ float4 bf2f4(ushort4 h) {
    float4 f;
    f.x = bf2f(h.x); f.y = bf2f(h.y); f.z = bf2f(h.z); f.w = bf2f(h.w);
    return f;
}

__device__ __forceinline__ void fma4(float4& acc, float xs, const float4& wv) {
    acc.x = fmaf(xs, wv.x, acc.x);
    acc.y = fmaf(xs, wv.y, acc.y);
    acc.z = fmaf(xs, wv.z, acc.z);
    acc.w = fmaf(xs, wv.w, acc.w);
}

// ---------------- build phase A: LDS-privatized radix partition ----------------

__global__ __launch_bounds__(1024) void k_part(const int* __restrict__ src,
                                               const int* __restrict__ dstv,
                                               int* __restrict__ pcur,
                                               int* __restrict__ plist, int E, int P) {
    __shared__ int hist_l[PMAX];
    __shared__ int base_l[PMAX];
    int e0 = blockIdx.x * EPB;
    int e1 = min(e0 + EPB, E);

    for (int i = threadIdx.x; i < P; i += 1024) hist_l[i] = 0;
    __syncthreads();

    for (int e = e0 + threadIdx.x; e < e1; e += 1024)
        atomicAdd(&hist_l[dstv[e] >> PSHIFT], 1);
    __syncthreads();

    for (int i = threadIdx.x; i < P; i += 1024)
        base_l[i] = atomicAdd(&pcur[i], hist_l[i]);
    __syncthreads();

    for (int e = e0 + threadIdx.x; e < e1; e += 1024) {
        int s = src[e], d = dstv[e];
        int p = d >> PSHIFT;
        int pos = atomicAdd(&base_l[p], 1);   // LDS atomic
        if (pos < CAPP)
            plist[(size_t)p * CAPP + pos] = (s << PSHIFT) | (d & (PNODES - 1));
    }
}

// ---------------- build phase B: per-partition slot build in LDS (+dis) ----------------

__global__ __launch_bounds__(256) void k_build2(const int* __restrict__ plist,
                                                const int* __restrict__ pcur,
                                                int* __restrict__ cnt,
                                                int* __restrict__ slots,
                                                float* __restrict__ dis, int N) {
    __shared__ int cnt_l[PNODES];          // 1 KB
    __shared__ int slots_l[PNODES * CAP];  // 48 KB
    int p = blockIdx.x;
    int node0 = p << PSHIFT;
    int nnodes = min(PNODES, N - node0);

    for (int t = threadIdx.x; t < PNODES; t += 256) cnt_l[t] = 0;
    __syncthreads();

    int nE = min(pcur[p], CAPP);
    for (int i = threadIdx.x; i < nE; i += 256) {
        int v = plist[(size_t)p * CAPP + i];
        int ln = v & (PNODES - 1);
        int s = (unsigned)v >> PSHIFT;
        int q = atomicAdd(&cnt_l[ln], 1);  // LDS atomic
        if (q < CAP) slots_l[ln * CAP + q] = s;
    }
    __syncthreads();

    for (int t = threadIdx.x; t < nnodes; t += 256) {
        int c = cnt_l[t];
        cnt[node0 + t] = c;
        dis[node0 + t] = rsqrtf((float)(c + 1));  // deg = indeg + self-loop
    }
    int tot = nnodes * CAP;
    int* gs = slots + (size_t)node0 * CAP;
    for (int i = threadIdx.x; i < tot; i += 256) gs[i] = slots_l[i];
}

// ---------------- MFMA GEMM: H(bf16) = X(fp32) @ W ----------------
// W split hi+lo bf16 (error 2^-17); X rounded to single bf16 (error 2^-9,
// same order as the bf16 H storage we already carry). H = Xhi@Whi + Xhi@Wlo:
// 4 MFMA per c-tile, no per-element lo-split VALU on the A path.
// W^T staged in LDS [n][k] with XOR swizzle ^((n&7)<<3) (kills the 16-way
// stride-256B ds_read_b128 conflict). Frag layouts: A row=l&15, k=(l>>4)*8+i
// (consistent on A and B cancels any k-permutation); C/D col=l&15,
// row=(l>>4)*4+reg [verified m89].

__global__ __launch_bounds__(256) void k_gemm(const float* __restrict__ X,
                                              const float* __restrict__ Wg,
                                              u16* __restrict__ H, int nchunks, int N) {
    __shared__ bf16_t sHi[D * D];  // 32 KB, W^T [n][k], swizzled
    __shared__ bf16_t sLo[D * D];  // 32 KB

    for (int i = threadIdx.x; i < D * D; i += 256) {
        int k = i >> 7, n = i & 127;        // Wg[i] = W[k][n], coalesced in n
        float w = Wg[i];
        bf16_t hi = (bf16_t)w;
        bf16_t lo = (bf16_t)(w - (float)hi);
        int idx = (n * D + k) ^ ((n & 7) << 3);
        sHi[idx] = hi;
        sLo[idx] = lo;
    }
    __syncthreads();

    int wv = threadIdx.x >> 6;   // wave 0..3
    int l  = threadIdx.x & 63;
    int lm = l & 15;             // A-row / B-col / C-col within tile
    int g  = l >> 4;             // k-group (A/B), row-group (C/D)

    for (int chunk = blockIdx.x; chunk < nchunks; chunk += gridDim.x) {
        int rowbase = chunk * 128 + wv * 32;
        if (rowbase >= N) continue;

        f32x4v acc[2][8];
#pragma unroll
        for (int rt = 0; rt < 2; ++rt)
#pragma unroll
            for (int c = 0; c < 8; ++c)
#pragma unroll
                for (int r = 0; r < 4; ++r) acc[rt][c][r] = 0.f;

#pragma unroll
        for (int t = 0; t < 4; ++t) {
            bf16x8 ahi[2];
#pragma unroll
            for (int rt = 0; rt < 2; ++rt) {
                int row = rowbase + rt * 16 + lm;
                int rc = row < N ? row : N - 1;          // clamp: loads safe, stores guarded
                const float4* xp = (const float4*)(X + (size_t)rc * D + t * 32 + g * 8);
                float4 f0 = xp[0];
                float4 f1 = xp[1];
                float fv[8] = {f0.x, f0.y, f0.z, f0.w, f1.x, f1.y, f1.z, f1.w};
#pragma unroll
                for (int i = 0; i < 8; ++i) ahi[rt][i] = (bf16_t)fv[i];
            }
#pragma unroll
            for (int c = 0; c < 8; ++c) {
                int idx = ((c * 16 + lm) * D + t * 32 + g * 8) ^ ((lm & 7) << 3);
                bf16x8 bhi = *(const bf16x8*)&sHi[idx];
                bf16x8 blo = *(const bf16x8*)&sLo[idx];
                acc[0][c] = __builtin_amdgcn_mfma_f32_16x16x32_bf16(ahi[0], bhi, acc[0][c], 0, 0, 0);
                acc[0][c] = __builtin_amdgcn_mfma_f32_16x16x32_bf16(ahi[0], blo, acc[0][c], 0, 0, 0);
                acc[1][c] = __builtin_amdgcn_mfma_f32_16x16x32_bf16(ahi[1], bhi, acc[1][c], 0, 0, 0);
                acc[1][c] = __builtin_amdgcn_mfma_f32_16x16x32_bf16(ahi[1], blo, acc[1][c], 0, 0, 0);
            }
        }

#pragma unroll
        for (int rt = 0; rt < 2; ++rt)
#pragma unroll
            for (int r = 0; r < 4; ++r) {
                int row = rowbase + rt * 16 + g * 4 + r;
                if (row >= N) continue;
                u16* hp = H + (size_t)row * D + lm;
#pragma unroll
                for (int c = 0; c < 8; ++c)
                    hp[c * 16] = f2bf(acc[rt][c][r]);
            }
    }
}

// ---------------- Aggregation: Y(fp32) = A_norm @ H(bf16) + b ----------------
// Half-wave (32 lanes x 4 bf16 = 256 B) per dst node; edge loop unrolled x8.
// At the measured service wall: ~200 MB compulsory 8-XCD H replication at
// ~3.5 TB/s (stable across r4/r11/r12 variants) -> ~73 us. Keep VGPR <= 36.

__global__ __launch_bounds__(256) void k_agg(const u16* __restrict__ H,
                                             const int* __restrict__ slots,
                                             const int* __restrict__ cnt,
                                             const float* __restrict__ dis,
                                             const float* __restrict__ bias,
                                             float* __restrict__ Y, int N, int relu) {
    int node = (blockIdx.x * 256 + threadIdx.x) >> 5;  // half-wave per node
    int lane = threadIdx.x & 31;
    if (node >= N) return;

    const ushort4* __restrict__ Hv = (const ushort4*)H;  // 32 ushort4 per row

    float ds = dis[node];
    float4 hv = bf2f4(Hv[(size_t)node * 32 + lane]);
    float wl = ds * ds;  // self-loop norm
    float4 acc;
    acc.x = wl * hv.x; acc.y = wl * hv.y; acc.z = wl * hv.z; acc.w = wl * hv.w;

    int n = cnt[node];
    if (n > CAP) n = CAP;
    const int* sp = slots + (size_t)node * CAP;

    int e = 0;
    for (; e + 8 <= n; e += 8) {
        int s0 = sp[e + 0], s1 = sp[e + 1], s2 = sp[e + 2], s3 = sp[e + 3];
        int s4 = sp[e + 4], s5 = sp[e + 5], s6 = sp[e + 6], s7 = sp[e + 7];
        ushort4 v0 = Hv[(size_t)s0 * 32 + lane];
        ushort4 v1 = Hv[(size_t)s1 * 32 + lane];
        ushort4 v2 = Hv[(size_t)s2 * 32 + lane];
        ushort4 v3 = Hv[(size_t)s3 * 32 + lane];
        ushort4 v4 = Hv[(size_t)s4 * 32 + lane];
        ushort4 v5 = Hv[(size_t)s5 * 32 + lane];
        ushort4 v6 = Hv[(size_t)s6 * 32 + lane];
        ushort4 v7 = Hv[(size_t)s7 * 32 + lane];
        float w0 = dis[s0] * ds, w1 = dis[s1] * ds, w2 = dis[s2] * ds, w3 = dis[s3] * ds;
        float w4 = dis[s4] * ds, w5 = dis[s5] * ds, w6 = dis[s6] * ds, w7 = dis[s7] * ds;
        fma4(acc, w0, bf2f4(v0));
        fma4(acc, w1, bf2f4(v1));
        fma4(acc, w2, bf2f4(v2));
        fma4(acc, w3, bf2f4(v3));
        fma4(acc, w4, bf2f4(v4));
        fma4(acc, w5, bf2f4(v5));
        fma4(acc, w6, bf2f4(v6));
        fma4(acc, w7, bf2f4(v7));
    }
    for (; e < n; ++e) {
        int s = sp[e];
        ushort4 v = Hv[(size_t)s * 32 + lane];
        fma4(acc, dis[s] * ds, bf2f4(v));
    }

    float4 bv = ((const float4*)bias)[lane];
    acc.x += bv.x; acc.y += bv.y; acc.z += bv.z; acc.w += bv.w;
    if (relu) {
        acc.x = fmaxf(acc.x, 0.f);
        acc.y = fmaxf(acc.y, 0.f);
        acc.z = fmaxf(acc.z, 0.f);
        acc.w = fmaxf(acc.w, 0.f);
    }
    ((float4*)(Y + (size_t)node * D))[lane] = acc;
}

// ---------------- launch ----------------

extern "C" void kernel_launch(void* const* d_in, const int* in_sizes, int n_in,
                              void* d_out, int out_size, void* d_ws, size_t ws_size,
                              hipStream_t stream) {
    const float* x  = (const float*)d_in[0];
    const int*   ei = (const int*)d_in[1];
    const float* W1 = (const float*)d_in[2];
    const float* b1 = (const float*)d_in[3];
    const float* W2 = (const float*)d_in[4];
    const float* b2 = (const float*)d_in[5];
    const float* W3 = (const float*)d_in[6];
    const float* b3 = (const float*)d_in[7];
    float* out = (float*)d_out;

    int N = in_sizes[0] / D;
    int E = in_sizes[1] / 2;
    const int* src  = ei;       // edge_index[0]
    const int* dstv = ei + E;   // edge_index[1]
    int P = (N + PNODES - 1) >> PSHIFT;  // 391

    char* ws = (char*)d_ws;
    size_t off = 0;
    auto alloc = [&](size_t bytes) -> void* {
        void* p = ws + off;
        off += (bytes + 255) & ~(size_t)255;
        return p;
    };
    u16*   Hbuf  = (u16*)alloc((size_t)N * D * sizeof(u16));        // 25.6 MB
    int*   cnt   = (int*)alloc((size_t)N * sizeof(int));            // 0.4 MB
    int*   slots = (int*)alloc((size_t)N * CAP * sizeof(int));      // 19.2 MB
    float* dis   = (float*)alloc((size_t)N * sizeof(float));        // 0.4 MB
    int*   pcur  = (int*)alloc((size_t)P * sizeof(int));            // 1.6 KB
    int*   plist = (int*)alloc((size_t)P * CAPP * sizeof(int));     // 9.6 MB

    int nchunks = (N + 127) / 128;     // 782 chunks of 128 rows
    int gemmgrid = (nchunks + 1) / 2;  // 391: exactly 2 chunks per block
    int aggblocks = (N + 7) / 8;
    int pablocks = (E + EPB - 1) / EPB;  // 196

    // --- build: partition -> LDS slot build(+dis) ---
    hipMemsetAsync(pcur, 0, (size_t)P * sizeof(int), stream);
    k_part<<<pablocks, 1024, 0, stream>>>(src, dstv, pcur, plist, E, P);
    k_build2<<<P, 256, 0, stream>>>(plist, pcur, cnt, slots, dis, N);

    // --- layer 1 ---
    k_gemm<<<gemmgrid, 256, 0, stream>>>(x, W1, Hbuf, nchunks, N);
    k_agg<<<aggblocks, 256, 0, stream>>>(Hbuf, slots, cnt, dis, b1, out, N, 1);

    // --- layer 2 ---
    k_gemm<<<gemmgrid, 256, 0, stream>>>(out, W2, Hbuf, nchunks, N);
    k_agg<<<aggblocks, 256, 0, stream>>>(Hbuf, slots, cnt, dis, b2, out, N, 1);

    // --- layer 3 (no relu) ---
    k_gemm<<<gemmgrid, 256, 0, stream>>>(out, W3, Hbuf, nchunks, N);
    k_agg<<<aggblocks, 256, 0, stream>>>(Hbuf, slots, cnt, dis, b3, out, N, 0);
}

// Round 14
// 304.979 us; speedup vs baseline: 1.1136x; 1.0510x over previous
//
#include <hip/hip_runtime.h>

#define D 128
#define CAP 48            // per-node slot capacity; max degree ~36 for Poisson(16)
#define PSHIFT 8
#define PNODES 256        // nodes per partition
#define PMAX 512          // compile-time max partitions (N <= 131072)
#define CAPP 6144         // per-partition edge capacity (mean 4092, sigma ~64)
#define EPB 8192          // edges per k_part block

typedef unsigned short u16;
typedef __bf16 bf16_t;
typedef bf16_t bf16x8 __attribute__((ext_vector_type(8)));
typedef float f32x4v __attribute__((ext_vector_type(4)));

// ---------------- bf16 helpers ----------------

__device__ __forceinline__ u16 f2bf(float f) {           // RNE
    unsigned u = __float_as_uint(f);
    return (u16)((u + 0x7FFFu + ((u >> 16) & 1u)) >> 16);
}

__device__ __forceinline__ float bf2f(u16 h) {
    return __uint_as_float((unsigned)h << 16);
}

__device__ __forceinline__ float4 bf2f4(ushort4 h) {
    float4 f;
    f.x = bf2f(h.x); f.y = bf2f(h.y); f.z = bf2f(h.z); f.w = bf2f(h.w);
    return f;
}

__device__ __forceinline__ void fma4(float4& acc, float xs, const float4& wv) {
    acc.x = fmaf(xs, wv.x, acc.x);
    acc.y = fmaf(xs, wv.y, acc.y);
    acc.z = fmaf(xs, wv.z, acc.z);
    acc.w = fmaf(xs, wv.w, acc.w);
}

// ---------------- build phase A: LDS-privatized radix partition ----------------

__global__ __launch_bounds__(1024) void k_part(const int* __restrict__ src,
                                               const int* __restrict__ dstv,
                                               int* __restrict__ pcur,
                                               int* __restrict__ plist, int E, int P) {
    __shared__ int hist_l[PMAX];
    __shared__ int base_l[PMAX];
    int e0 = blockIdx.x * EPB;
    int e1 = min(e0 + EPB, E);

    for (int i = threadIdx.x; i < P; i += 1024) hist_l[i] = 0;
    __syncthreads();

    for (int e = e0 + threadIdx.x; e < e1; e += 1024)
        atomicAdd(&hist_l[dstv[e] >> PSHIFT], 1);
    __syncthreads();

    for (int i = threadIdx.x; i < P; i += 1024)
        base_l[i] = atomicAdd(&pcur[i], hist_l[i]);
    __syncthreads();

    for (int e = e0 + threadIdx.x; e < e1; e += 1024) {
        int s = src[e], d = dstv[e];
        int p = d >> PSHIFT;
        int pos = atomicAdd(&base_l[p], 1);   // LDS atomic
        if (pos < CAPP)
            plist[(size_t)p * CAPP + pos] = (s << PSHIFT) | (d & (PNODES - 1));
    }
}

// ---------------- build phase B: per-partition slot build in LDS (+dis) ----------------

__global__ __launch_bounds__(256) void k_build2(const int* __restrict__ plist,
                                                const int* __restrict__ pcur,
                                                int* __restrict__ cnt,
                                                int* __restrict__ slots,
                                                float* __restrict__ dis, int N) {
    __shared__ int cnt_l[PNODES];          // 1 KB
    __shared__ int slots_l[PNODES * CAP];  // 48 KB
    int p = blockIdx.x;
    int node0 = p << PSHIFT;
    int nnodes = min(PNODES, N - node0);

    for (int t = threadIdx.x; t < PNODES; t += 256) cnt_l[t] = 0;
    __syncthreads();

    int nE = min(pcur[p], CAPP);
    for (int i = threadIdx.x; i < nE; i += 256) {
        int v = plist[(size_t)p * CAPP + i];
        int ln = v & (PNODES - 1);
        int s = (unsigned)v >> PSHIFT;
        int q = atomicAdd(&cnt_l[ln], 1);  // LDS atomic
        if (q < CAP) slots_l[ln * CAP + q] = s;
    }
    __syncthreads();

    for (int t = threadIdx.x; t < nnodes; t += 256) {
        int c = cnt_l[t];
        cnt[node0 + t] = c;
        dis[node0 + t] = rsqrtf((float)(c + 1));  // deg = indeg + self-loop
    }
    int tot = nnodes * CAP;
    int* gs = slots + (size_t)node0 * CAP;
    for (int i = threadIdx.x; i < tot; i += 256) gs[i] = slots_l[i];
}

// ---------------- MFMA GEMM: H(bf16) = X @ W ----------------
// W split hi+lo bf16; X rounded to bf16 (XBF=0: fp32 input, convert in-reg;
// XBF=1: input already bf16, single 16 B A-load, no convert VALU).
// 512 threads = 8 waves x 16 rows -> acc is 8 x f32x4 (32 VGPR), 64 KB W-LDS
// -> 2 blocks/CU = 16 waves/CU (50% occ; was 25% at 256 thr / 64-VGPR acc).
// W^T staged [n][k] with XOR swizzle ^((n&7)<<3). Frag layouts: A row=l&15,
// k=(l>>4)*8+i (consistent on A and B); C/D col=l&15, row=(l>>4)*4+reg [m89].

template <int XBF>
__global__ __launch_bounds__(512) void k_gemm(const void* __restrict__ Xv,
                                              const float* __restrict__ Wg,
                                              u16* __restrict__ H, int nchunks, int N) {
    __shared__ bf16_t sHi[D * D];  // 32 KB, W^T [n][k], swizzled
    __shared__ bf16_t sLo[D * D];  // 32 KB

    for (int i = threadIdx.x; i < D * D; i += 512) {
        int k = i >> 7, n = i & 127;        // Wg[i] = W[k][n], coalesced in n
        float w = Wg[i];
        bf16_t hi = (bf16_t)w;
        bf16_t lo = (bf16_t)(w - (float)hi);
        int idx = (n * D + k) ^ ((n & 7) << 3);
        sHi[idx] = hi;
        sLo[idx] = lo;
    }
    __syncthreads();

    int wv = threadIdx.x >> 6;   // wave 0..7, 16 rows each
    int l  = threadIdx.x & 63;
    int lm = l & 15;             // A-row / B-col / C-col within tile
    int g  = l >> 4;             // k-group (A/B), row-group (C/D)

    for (int chunk = blockIdx.x; chunk < nchunks; chunk += gridDim.x) {
        int rowbase = chunk * 128 + wv * 16;
        if (rowbase >= N) continue;          // N%16==0 -> resident waves fully valid

        f32x4v acc[8];
#pragma unroll
        for (int c = 0; c < 8; ++c)
#pragma unroll
            for (int r = 0; r < 4; ++r) acc[c][r] = 0.f;

#pragma unroll
        for (int t = 0; t < 4; ++t) {
            bf16x8 ahi;
            int row = rowbase + lm;
            if constexpr (XBF) {
                const u16* X = (const u16*)Xv;
                ahi = *(const bf16x8*)(X + (size_t)row * D + t * 32 + g * 8);
            } else {
                const float* X = (const float*)Xv;
                const float4* xp = (const float4*)(X + (size_t)row * D + t * 32 + g * 8);
                float4 f0 = xp[0];
                float4 f1 = xp[1];
                float fv[8] = {f0.x, f0.y, f0.z, f0.w, f1.x, f1.y, f1.z, f1.w};
#pragma unroll
                for (int i = 0; i < 8; ++i) ahi[i] = (bf16_t)fv[i];
            }
#pragma unroll
            for (int c = 0; c < 8; ++c) {
                int idx = ((c * 16 + lm) * D + t * 32 + g * 8) ^ ((lm & 7) << 3);
                bf16x8 bhi = *(const bf16x8*)&sHi[idx];
                bf16x8 blo = *(const bf16x8*)&sLo[idx];
                acc[c] = __builtin_amdgcn_mfma_f32_16x16x32_bf16(ahi, bhi, acc[c], 0, 0, 0);
                acc[c] = __builtin_amdgcn_mfma_f32_16x16x32_bf16(ahi, blo, acc[c], 0, 0, 0);
            }
        }

#pragma unroll
        for (int r = 0; r < 4; ++r) {
            int row = rowbase + g * 4 + r;
            if (row >= N) continue;
            u16* hp = H + (size_t)row * D + lm;
#pragma unroll
            for (int c = 0; c < 8; ++c)
                hp[c * 16] = f2bf(acc[c][r]);
        }
    }
}

// ---------------- Aggregation: Y = A_norm @ H(bf16) + b ----------------
// Half-wave (32 lanes x 4 bf16 = 256 B) per dst node; edge loop unrolled x8.
// At measured floor: ~200 MB compulsory 8-XCD H replication at ~3.45 TB/s.
// mode=1: relu + bf16 store (intermediate layers); mode=0: fp32 store (final).

__global__ __launch_bounds__(256) void k_agg(const u16* __restrict__ H,
                                             const int* __restrict__ slots,
                                             const int* __restrict__ cnt,
                                             const float* __restrict__ dis,
                                             const float* __restrict__ bias,
                                             u16* __restrict__ Ybf,
                                             float* __restrict__ Yf,
                                             int N, int mode) {
    int node = (blockIdx.x * 256 + threadIdx.x) >> 5;  // half-wave per node
    int lane = threadIdx.x & 31;
    if (node >= N) return;

    const ushort4* __restrict__ Hv = (const ushort4*)H;  // 32 ushort4 per row

    float ds = dis[node];
    float4 hv = bf2f4(Hv[(size_t)node * 32 + lane]);
    float wl = ds * ds;  // self-loop norm
    float4 acc;
    acc.x = wl * hv.x; acc.y = wl * hv.y; acc.z = wl * hv.z; acc.w = wl * hv.w;

    int n = cnt[node];
    if (n > CAP) n = CAP;
    const int* sp = slots + (size_t)node * CAP;

    int e = 0;
    for (; e + 8 <= n; e += 8) {
        int s0 = sp[e + 0], s1 = sp[e + 1], s2 = sp[e + 2], s3 = sp[e + 3];
        int s4 = sp[e + 4], s5 = sp[e + 5], s6 = sp[e + 6], s7 = sp[e + 7];
        ushort4 v0 = Hv[(size_t)s0 * 32 + lane];
        ushort4 v1 = Hv[(size_t)s1 * 32 + lane];
        ushort4 v2 = Hv[(size_t)s2 * 32 + lane];
        ushort4 v3 = Hv[(size_t)s3 * 32 + lane];
        ushort4 v4 = Hv[(size_t)s4 * 32 + lane];
        ushort4 v5 = Hv[(size_t)s5 * 32 + lane];
        ushort4 v6 = Hv[(size_t)s6 * 32 + lane];
        ushort4 v7 = Hv[(size_t)s7 * 32 + lane];
        float w0 = dis[s0] * ds, w1 = dis[s1] * ds, w2 = dis[s2] * ds, w3 = dis[s3] * ds;
        float w4 = dis[s4] * ds, w5 = dis[s5] * ds, w6 = dis[s6] * ds, w7 = dis[s7] * ds;
        fma4(acc, w0, bf2f4(v0));
        fma4(acc, w1, bf2f4(v1));
        fma4(acc, w2, bf2f4(v2));
        fma4(acc, w3, bf2f4(v3));
        fma4(acc, w4, bf2f4(v4));
        fma4(acc, w5, bf2f4(v5));
        fma4(acc, w6, bf2f4(v6));
        fma4(acc, w7, bf2f4(v7));
    }
    for (; e < n; ++e) {
        int s = sp[e];
        ushort4 v = Hv[(size_t)s * 32 + lane];
        fma4(acc, dis[s] * ds, bf2f4(v));
    }

    float4 bv = ((const float4*)bias)[lane];
    acc.x += bv.x; acc.y += bv.y; acc.z += bv.z; acc.w += bv.w;
    if (mode) {  // relu + bf16 store
        acc.x = fmaxf(acc.x, 0.f);
        acc.y = fmaxf(acc.y, 0.f);
        acc.z = fmaxf(acc.z, 0.f);
        acc.w = fmaxf(acc.w, 0.f);
        ushort4 o;
        o.x = f2bf(acc.x); o.y = f2bf(acc.y); o.z = f2bf(acc.z); o.w = f2bf(acc.w);
        ((ushort4*)(Ybf + (size_t)node * D))[lane] = o;
    } else {
        ((float4*)(Yf + (size_t)node * D))[lane] = acc;
    }
}

// ---------------- launch ----------------

extern "C" void kernel_launch(void* const* d_in, const int* in_sizes, int n_in,
                              void* d_out, int out_size, void* d_ws, size_t ws_size,
                              hipStream_t stream) {
    const float* x  = (const float*)d_in[0];
    const int*   ei = (const int*)d_in[1];
    const float* W1 = (const float*)d_in[2];
    const float* b1 = (const float*)d_in[3];
    const float* W2 = (const float*)d_in[4];
    const float* b2 = (const float*)d_in[5];
    const float* W3 = (const float*)d_in[6];
    const float* b3 = (const float*)d_in[7];
    float* out = (float*)d_out;

    int N = in_sizes[0] / D;
    int E = in_sizes[1] / 2;
    const int* src  = ei;       // edge_index[0]
    const int* dstv = ei + E;   // edge_index[1]
    int P = (N + PNODES - 1) >> PSHIFT;  // 391

    char* ws = (char*)d_ws;
    size_t off = 0;
    auto alloc = [&](size_t bytes) -> void* {
        void* p = ws + off;
        off += (bytes + 255) & ~(size_t)255;
        return p;
    };
    u16*   Hbuf  = (u16*)alloc((size_t)N * D * sizeof(u16));        // 25.6 MB
    u16*   Ybf   = (u16*)alloc((size_t)N * D * sizeof(u16));        // 25.6 MB
    int*   cnt   = (int*)alloc((size_t)N * sizeof(int));            // 0.4 MB
    int*   slots = (int*)alloc((size_t)N * CAP * sizeof(int));      // 19.2 MB
    float* dis   = (float*)alloc((size_t)N * sizeof(float));        // 0.4 MB
    int*   pcur  = (int*)alloc((size_t)P * sizeof(int));            // 1.6 KB
    int*   plist = (int*)alloc((size_t)P * CAPP * sizeof(int));     // 9.6 MB

    int nchunks = (N + 127) / 128;     // 782 chunks of 128 rows (8 waves x 16)
    int gemmgrid = 512;                // 2 blocks/CU resident, grid-stride
    int aggblocks = (N + 7) / 8;
    int pablocks = (E + EPB - 1) / EPB;  // 196

    // --- build: partition -> LDS slot build(+dis) ---
    hipMemsetAsync(pcur, 0, (size_t)P * sizeof(int), stream);
    k_part<<<pablocks, 1024, 0, stream>>>(src, dstv, pcur, plist, E, P);
    k_build2<<<P, 256, 0, stream>>>(plist, pcur, cnt, slots, dis, N);

    // --- layer 1: fp32 x -> H; agg(relu) -> Ybf (bf16) ---
    k_gemm<0><<<gemmgrid, 512, 0, stream>>>(x, W1, Hbuf, nchunks, N);
    k_agg<<<aggblocks, 256, 0, stream>>>(Hbuf, slots, cnt, dis, b1, Ybf, nullptr, N, 1);

    // --- layer 2: bf16 Ybf -> H; agg(relu) -> Ybf ---
    k_gemm<1><<<gemmgrid, 512, 0, stream>>>(Ybf, W2, Hbuf, nchunks, N);
    k_agg<<<aggblocks, 256, 0, stream>>>(Hbuf, slots, cnt, dis, b2, Ybf, nullptr, N, 1);

    // --- layer 3: bf16 Ybf -> H; agg -> out (fp32, no relu) ---
    k_gemm<1><<<gemmgrid, 512, 0, stream>>>(Ybf, W3, Hbuf, nchunks, N);
    k_agg<<<aggblocks, 256, 0, stream>>>(Hbuf, slots, cnt, dis, b3, nullptr, out, N, 0);
}